// Round 14
// baseline (178.817 us; speedup 1.0000x reference)
//
#include <hip/hip_runtime.h>
#include <hip/hip_bf16.h>
#include <cstdint>
#include <cstddef>

#define IN_F 128
#define HID 128
#define NH1 4
#define OUTF 64
#define NBMAX 512   // buckets of 128 nodes -> supports N <= 65536
#define CH 2048     // edges per bfill chunk
#define NBFILL 256  // bfill blocks

typedef __attribute__((ext_vector_type(8))) short short8;
typedef __attribute__((ext_vector_type(4))) float f32x4;

__device__ __forceinline__ float lrelu(float v) { return v > 0.f ? v : 0.2f * v; }
__device__ __forceinline__ float eluf(float v) { return v > 0.f ? v : (__expf(v) - 1.f); }
__device__ __forceinline__ unsigned f2bf(float f) {
  unsigned u = __float_as_uint(f);
  return (u + 0x7fffu + ((u >> 16) & 1u)) >> 16;
}
__device__ __forceinline__ float bflo(unsigned hv) { return __uint_as_float(hv << 16); }
__device__ __forceinline__ float bfhi(unsigned hv) { return __uint_as_float(hv & 0xffff0000u); }

// ---------------------------------------------------------------- fused prep + bucket histogram
__global__ __launch_bounds__(256) void k_pb(
    const float* __restrict__ x, const float* __restrict__ W1, const float* __restrict__ W2,
    const int* __restrict__ dst, int E,
    unsigned short* __restrict__ xb, unsigned short* __restrict__ wt,
    unsigned short* __restrict__ wt2, int* __restrict__ gbcnt, int nx4) {
  __shared__ int bcnt[NBMAX];
  if (blockIdx.x < 512) {
    const int t = threadIdx.x;
    bcnt[t] = 0; bcnt[t + 256] = 0;
    __syncthreads();
    for (int e = blockIdx.x * 256 + t; e < E; e += 512 * 256)
      atomicAdd(&bcnt[dst[e] >> 7], 1);
    __syncthreads();
    for (int b = t; b < NBMAX; b += 256)
      if (bcnt[b]) atomicAdd(&gbcnt[b], bcnt[b]);
    return;
  }
  const int t = (blockIdx.x - 512) * 256 + threadIdx.x;
  if (t < nx4) {
    const float4 v = ((const float4*)x)[t];
    uint2 u;
    u.x = f2bf(v.x) | (f2bf(v.y) << 16);
    u.y = f2bf(v.z) | (f2bf(v.w) << 16);
    ((uint2*)xb)[t] = u;
  }
  if (t < IN_F * HID) {
    const int k = t >> 7, c = t & 127;
    const int chunk = k >> 3;
    const int csw = (chunk & 8) | ((chunk ^ (c & 7)) & 7);
    wt[c * 128 + csw * 8 + (k & 7)] = (unsigned short)f2bf(W1[t]);
  }
  if (t < HID * OUTF) {
    const int k = t >> 6, c = t & 63;
    const int chunk = k >> 3;
    const int csw = (chunk & 8) | ((chunk ^ (c & 7)) & 7);
    wt2[c * 128 + csw * 8 + (k & 7)] = (unsigned short)f2bf(W2[t]);
  }
}

// ---------------------------------------------------------------- bucket scan (one block, 512 thr)
__global__ __launch_bounds__(512) void k_bscan(const int* __restrict__ gbcnt,
                                               int* __restrict__ sbase,
                                               int* __restrict__ gcursor,
                                               int* __restrict__ csrbase,
                                               int NB, int N) {
  __shared__ int tmp[NBMAX];
  const int t = threadIdx.x;
  const int g = (t < NB) ? gbcnt[t] : 0;
  const int nsz = (t < NB) ? min(128, N - t * 128) : 0;
  tmp[t] = g;
  __syncthreads();
  #pragma unroll
  for (int off = 1; off < NBMAX; off <<= 1) {
    const int v = (t >= off) ? tmp[t - off] : 0;
    __syncthreads();
    tmp[t] += v;
    __syncthreads();
  }
  const int sb = tmp[t] - g;
  if (t < NB) { sbase[t] = sb; gcursor[t] = sb; }
  __syncthreads();
  tmp[t] = g + nsz;
  __syncthreads();
  #pragma unroll
  for (int off = 1; off < NBMAX; off <<= 1) {
    const int v = (t >= off) ? tmp[t - off] : 0;
    __syncthreads();
    tmp[t] += v;
    __syncthreads();
  }
  if (t < NB) csrbase[t] = tmp[t] - (g + nsz);
}

// ---------------------------------------------------------------- fused layer-1 MFMA GEMM + bfill
// h16 packed as adjacent col pairs: uint j = cols (2j, 2j+1).
__global__ __launch_bounds__(256) void k_g1bf(
    const unsigned short* __restrict__ xb, const unsigned short* __restrict__ wt,
    const float* __restrict__ a_s, const float* __restrict__ a_d,
    unsigned* __restrict__ h16, float* __restrict__ als, float* __restrict__ ald, int N,
    const int* __restrict__ src, const int* __restrict__ dst, int E,
    int* __restrict__ gcursor, unsigned* __restrict__ stage, int NG1) {
  __shared__ __align__(16) unsigned char smem[32768];
  if ((int)blockIdx.x >= NG1) {
    int* bcnt = (int*)smem;
    int* bofs = bcnt + NBMAX;
    int* lcur = bofs + NBMAX;
    int* gofs = lcur + NBMAX;
    unsigned* obuf = (unsigned*)(smem + 8192);
    unsigned short* bid = (unsigned short*)(smem + 16384);
    const int t = threadIdx.x;
    const int b = blockIdx.x - NG1;
    for (int base_e = b * CH; base_e < E; base_e += NBFILL * CH) {
      const int cnt = min(CH, E - base_e);
      __syncthreads();
      bcnt[t] = 0; bcnt[t + 256] = 0;
      __syncthreads();
      for (int i = t; i < cnt; i += 256)
        atomicAdd(&bcnt[dst[base_e + i] >> 7], 1);
      __syncthreads();
      bofs[t] = bcnt[t]; bofs[t + 256] = bcnt[t + 256];
      __syncthreads();
      #pragma unroll
      for (int off = 1; off < NBMAX; off <<= 1) {
        const int v0 = (t >= off) ? bofs[t - off] : 0;
        const int v1 = (t + 256 >= off) ? bofs[t + 256 - off] : 0;
        __syncthreads();
        bofs[t] += v0; bofs[t + 256] += v1;
        __syncthreads();
      }
      {
        const int e0 = bofs[t] - bcnt[t], e1 = bofs[t + 256] - bcnt[t + 256];
        __syncthreads();
        bofs[t] = e0;        bofs[t + 256] = e1;
        lcur[t] = e0;        lcur[t + 256] = e1;
      }
      __syncthreads();
      for (int i = t; i < cnt; i += 256) {
        const int d = dst[base_e + i];
        const int bb = d >> 7;
        const int pos = atomicAdd(&lcur[bb], 1);
        obuf[pos] = ((unsigned)(d & 127) << 25) | (unsigned)src[base_e + i];
        bid[pos] = (unsigned short)bb;
      }
      __syncthreads();
      for (int bb = t; bb < NBMAX; bb += 256)
        if (bcnt[bb] > 0) gofs[bb] = atomicAdd(&gcursor[bb], bcnt[bb]);
      __syncthreads();
      for (int i = t; i < cnt; i += 256) {
        const int bb = bid[i];
        stage[gofs[bb] + (i - bofs[bb])] = obuf[i];
      }
    }
    return;
  }
  // ---- gemm1 body ----
  unsigned short* Wl = (unsigned short*)smem;
  const int wave = threadIdx.x >> 6, lane = threadIdx.x & 63;
  for (int i = threadIdx.x * 8; i < IN_F * HID; i += 256 * 8)
    *(short8*)(Wl + i) = *(const short8*)(wt + i);
  __syncthreads();
  const int li = lane & 15, g = lane >> 4;
  const int r0w = blockIdx.x * 64 + wave * 16;
  if (r0w >= N) return;
  float asp[8], adp[8];
  #pragma unroll
  for (int nt = 0; nt < 8; ++nt) { asp[nt] = a_s[16 * nt + li]; adp[nt] = a_d[16 * nt + li]; }
  f32x4 acc[8];
  #pragma unroll
  for (int nt = 0; nt < 8; ++nt) acc[nt] = (f32x4){0.f, 0.f, 0.f, 0.f};
  const int arow = min(r0w + li, N - 1);
  const unsigned short* xrow = xb + (size_t)arow * IN_F;
  #pragma unroll
  for (int s = 0; s < 4; ++s) {
    const short8 a = *(const short8*)(xrow + 32 * s + g * 8);
    const int chunk = 4 * s + g;
    const int csw = (chunk & 8) | ((chunk ^ (li & 7)) & 7);
    const unsigned short* bbase = Wl + li * 128 + csw * 8;
    #pragma unroll
    for (int nt = 0; nt < 8; ++nt) {
      const short8 bfr = *(const short8*)(bbase + nt * 2048);
      acc[nt] = __builtin_amdgcn_mfma_f32_16x16x32_bf16(a, bfr, acc[nt], 0, 0, 0);
    }
  }
  // h16: adjacent col pairs (2j, 2j+1) via lane-pair exchange
  #pragma unroll
  for (int r = 0; r < 4; ++r) {
    const int row = r0w + g * 4 + r;
    #pragma unroll
    for (int nt = 0; nt < 8; ++nt) {
      const float v = acc[nt][r];
      const float vn = __shfl_xor(v, 1, 64);
      if (!(li & 1) && row < N)
        h16[(size_t)row * 64 + 8 * nt + (li >> 1)] = f2bf(v) | (f2bf(vn) << 16);
    }
  }
  #pragma unroll
  for (int r = 0; r < 4; ++r) {
    const int row = r0w + g * 4 + r;
    #pragma unroll
    for (int hh = 0; hh < 4; ++hh) {
      float ps = acc[2 * hh][r] * asp[2 * hh] + acc[2 * hh + 1][r] * asp[2 * hh + 1];
      float pd = acc[2 * hh][r] * adp[2 * hh] + acc[2 * hh + 1][r] * adp[2 * hh + 1];
      #pragma unroll
      for (int mk = 1; mk <= 8; mk <<= 1) {
        ps += __shfl_xor(ps, mk, 16);
        pd += __shfl_xor(pd, mk, 16);
      }
      if (li == 0 && row < N) {
        als[row * NH1 + hh] = ps;
        ald[row * NH1 + hh] = pd;
      }
    }
  }
}

// ---------------------------------------------------------------- per-bucket CSR finalize
__global__ __launch_bounds__(256) void k_build(const unsigned* __restrict__ stage,
                                               const int* __restrict__ sbase,
                                               const int* __restrict__ gbcnt,
                                               const int* __restrict__ csrbase,
                                               int* __restrict__ rowptr,
                                               int* __restrict__ counts,
                                               int* __restrict__ csr, int N) {
  __shared__ int lc[128], lofs[128], lcur[128];
  const int b = blockIdx.x;
  const int t = threadIdx.x;
  const int n0 = b << 7;
  const int nn = min(128, N - n0);
  if (t < 128) lc[t] = (t < nn) ? 1 : 0;
  __syncthreads();
  const int s0 = sbase[b], ecnt = gbcnt[b];
  for (int i = t; i < ecnt; i += 256)
    atomicAdd(&lc[stage[s0 + i] >> 25], 1);
  __syncthreads();
  if (t < 128) lofs[t] = lc[t];
  __syncthreads();
  #pragma unroll
  for (int off = 1; off < 128; off <<= 1) {
    const int v = (t >= off && t < 128) ? lofs[t - off] : 0;
    __syncthreads();
    if (t < 128) lofs[t] += v;
    __syncthreads();
  }
  const int base = csrbase[b];
  if (t < nn) {
    const int ex = lofs[t] - lc[t];
    const int r = base + ex;
    rowptr[n0 + t] = r;
    counts[n0 + t] = lc[t];
    csr[r] = n0 + t;
    lcur[t] = ex + 1;
  }
  __syncthreads();
  for (int i = t; i < ecnt; i += 256) {
    const unsigned e = stage[s0 + i];
    const int d = e >> 25;
    const int pos = atomicAdd(&lcur[d], 1);
    csr[base + pos] = (int)(e & 0x1FFFFFFu);
  }
}

// ---------------------------------------------------------------- layer-2 GEMM: bf16 MFMA
__global__ __launch_bounds__(256) void k_gemm2(
    const unsigned short* __restrict__ hb, const unsigned short* __restrict__ wt2,
    const float* __restrict__ a_s, const float* __restrict__ a_d,
    unsigned* __restrict__ h16, float* __restrict__ als, float* __restrict__ ald, int N) {
  __shared__ unsigned short Wl[OUTF * HID];  // 16 KB
  const int wave = threadIdx.x >> 6, lane = threadIdx.x & 63;
  for (int i = threadIdx.x * 8; i < OUTF * HID; i += 256 * 8)
    *(short8*)(Wl + i) = *(const short8*)(wt2 + i);
  __syncthreads();
  const int li = lane & 15, g = lane >> 4;
  const int r0w = blockIdx.x * 64 + wave * 16;
  if (r0w >= N) return;
  float asp[4], adp[4];
  #pragma unroll
  for (int nt = 0; nt < 4; ++nt) { asp[nt] = a_s[16 * nt + li]; adp[nt] = a_d[16 * nt + li]; }
  f32x4 acc[4];
  #pragma unroll
  for (int nt = 0; nt < 4; ++nt) acc[nt] = (f32x4){0.f, 0.f, 0.f, 0.f};
  const int arow = min(r0w + li, N - 1);
  const unsigned short* xrow = hb + (size_t)arow * HID;
  #pragma unroll
  for (int s = 0; s < 4; ++s) {
    const short8 a = *(const short8*)(xrow + 32 * s + g * 8);
    const int chunk = 4 * s + g;
    const int csw = (chunk & 8) | ((chunk ^ (li & 7)) & 7);
    const unsigned short* bbase = Wl + li * 128 + csw * 8;
    #pragma unroll
    for (int nt = 0; nt < 4; ++nt) {
      const short8 bfr = *(const short8*)(bbase + nt * 2048);
      acc[nt] = __builtin_amdgcn_mfma_f32_16x16x32_bf16(a, bfr, acc[nt], 0, 0, 0);
    }
  }
  #pragma unroll
  for (int r = 0; r < 4; ++r) {
    const int row = r0w + g * 4 + r;
    #pragma unroll
    for (int nt = 0; nt < 4; ++nt) {
      const float v = acc[nt][r];
      const float vn = __shfl_xor(v, 1, 64);
      if (!(li & 1) && row < N)
        h16[(size_t)row * 32 + 8 * nt + (li >> 1)] = f2bf(v) | (f2bf(vn) << 16);
    }
  }
  #pragma unroll
  for (int r = 0; r < 4; ++r) {
    const int row = r0w + g * 4 + r;
    float ps = 0.f, pd = 0.f;
    #pragma unroll
    for (int nt = 0; nt < 4; ++nt) { ps += acc[nt][r] * asp[nt]; pd += acc[nt][r] * adp[nt]; }
    #pragma unroll
    for (int mk = 1; mk <= 8; mk <<= 1) {
      ps += __shfl_xor(ps, mk, 16);
      pd += __shfl_xor(pd, mk, 16);
    }
    if (li == 0 && row < N) { als[row] = ps; ald[row] = pd; }
  }
}

// ---------------------------------------------------------------- aggr1 half-pass (cols 64H..64H+63, heads 2H..2H+1)
// wave per dst; 16-edge batches; 2 edges per gather instr (eo = lane>>5);
// lane covers uint c = lane&31 -> cols (64H+2c, 64H+2c+1), head 2H+(c>>4).
template <int HALF>
__global__ __launch_bounds__(256) void k_aggr1(
    const int* __restrict__ rowptr, const int* __restrict__ counts,
    const int* __restrict__ csr,
    const float* __restrict__ als, const float* __restrict__ ald,
    const unsigned* __restrict__ h16, const float* __restrict__ b,
    unsigned short* __restrict__ outb, int N) {
  const int lane = threadIdx.x & 63;
  const int d = blockIdx.x * 4 + (threadIdx.x >> 6);
  if (d >= N) return;
  const int row0 = rowptr[d], deg = counts[d];
  const int c = lane & 31;
  const int eo = lane >> 5;
  const int headP = 2 * HALF + (lane & 1);     // p-lane's head
  const float aldP = ald[d * NH1 + headP];
  const float b0 = b[64 * HALF + 2 * c], b1 = b[64 * HALF + 2 * c + 1];
  float psum = 0.f, a0 = 0.f, a1 = 0.f;
  int i = 0;
  for (; i + 16 <= deg; i += 16) {
    const int sl = (lane < 16) ? csr[row0 + i + lane] : 0;
    const int se = __shfl(sl, lane >> 1, 64);          // lanes<32: edge lane>>1
    const float pv = __expf(lrelu(als[se * NH1 + headP] + aldP));
    if (lane < 32) psum += pv;
    #pragma unroll
    for (int q = 0; q < 8; ++q) {
      const int j = 2 * q + eo;
      const int s = __shfl(sl, j, 64);
      const float p = __shfl(pv, 2 * j + (c >> 4), 64);
      const unsigned hv = h16[(size_t)s * 64 + 32 * HALF + c];
      a0 += p * bflo(hv);
      a1 += p * bfhi(hv);
    }
  }
  if (i < deg) {  // masked tail (rem in [1,15])
    const int rem = deg - i;
    const int sl = (lane < 16) ? csr[row0 + i + min(lane, rem - 1)] : 0;
    const int se = __shfl(sl, lane >> 1, 64);
    float pv = __expf(lrelu(als[se * NH1 + headP] + aldP));
    if ((lane >> 1) >= rem) pv = 0.f;
    if (lane < 32) psum += pv;
    #pragma unroll
    for (int q = 0; q < 8; ++q) {
      const int j = 2 * q + eo;
      const int s = __shfl(sl, j, 64);
      const float p = __shfl(pv, 2 * j + (c >> 4), 64);
      const unsigned hv = h16[(size_t)s * 64 + 32 * HALF + c];
      a0 += p * bflo(hv);
      a1 += p * bfhi(hv);
    }
  }
  // per-parity head sums within lanes 0..31
  #pragma unroll
  for (int mk = 2; mk <= 16; mk <<= 1) psum += __shfl_xor(psum, mk, 32);
  const float sum = __shfl(psum, c >> 4, 64);  // lane0: head 2H; lane1: head 2H+1
  a0 += __shfl_xor(a0, 32, 64);
  a1 += __shfl_xor(a1, 32, 64);
  if (lane < 32) {
    const float r = 1.f / (sum + 1e-16f);
    const unsigned u = f2bf(eluf(a0 * r + b0)) | (f2bf(eluf(a1 * r + b1)) << 16);
    ((unsigned*)(outb + (size_t)d * HID + 64 * HALF))[c] = u;
  }
}

// ---------------------------------------------------------------- aggr2 half-pass (cols 32H..32H+31)
// wave per dst; 32-edge batches; 4 edges per gather instr (g4 = lane>>4);
// lane covers uint c = lane&15 -> cols (32H+2c, 32H+2c+1).
template <int HALF>
__global__ __launch_bounds__(256) void k_aggr2(
    const int* __restrict__ rowptr, const int* __restrict__ counts,
    const int* __restrict__ csr,
    const float* __restrict__ als, const float* __restrict__ ald,
    const unsigned* __restrict__ h16, const float* __restrict__ b,
    float* __restrict__ out, int N) {
  const int lane = threadIdx.x & 63;
  const int d = blockIdx.x * 4 + (threadIdx.x >> 6);
  if (d >= N) return;
  const int row0 = rowptr[d], deg = counts[d];
  const float aldd = ald[d];
  const int g4 = lane >> 4;
  const int c = lane & 15;
  float psum = 0.f, a0 = 0.f, a1 = 0.f;
  int i = 0;
  for (; i + 32 <= deg; i += 32) {
    const int sl = (lane < 32) ? csr[row0 + i + lane] : 0;
    const float pv = __expf(lrelu(als[sl] + aldd));
    if (lane < 32) psum += pv;
    #pragma unroll
    for (int q = 0; q < 8; ++q) {
      const int j = 4 * q + g4;
      const int s = __shfl(sl, j, 64);
      const float p = __shfl(pv, j, 64);
      const unsigned hv = h16[(size_t)s * 32 + 16 * HALF + c];
      a0 += p * bflo(hv);
      a1 += p * bfhi(hv);
    }
  }
  if (i < deg) {  // masked tail (rem in [1,31])
    const int rem = deg - i;
    const int sl = (lane < 32) ? csr[row0 + i + min(lane, rem - 1)] : 0;
    float pv = __expf(lrelu(als[sl] + aldd));
    if (lane >= rem) pv = 0.f;
    if (lane < 32) psum += pv;
    #pragma unroll
    for (int q = 0; q < 8; ++q) {
      const int j = 4 * q + g4;
      const int s = __shfl(sl, j, 64);
      const float p = __shfl(pv, j, 64);
      const unsigned hv = h16[(size_t)s * 32 + 16 * HALF + c];
      a0 += p * bflo(hv);
      a1 += p * bfhi(hv);
    }
  }
  #pragma unroll
  for (int mk = 1; mk <= 16; mk <<= 1) psum += __shfl_xor(psum, mk, 32);
  const float sum = __shfl(psum, 0, 64);
  a0 += __shfl_xor(a0, 16, 64);
  a1 += __shfl_xor(a1, 16, 64);
  a0 += __shfl_xor(a0, 32, 64);
  a1 += __shfl_xor(a1, 32, 64);
  if (lane < 16) {
    const float r = 1.f / (sum + 1e-16f);
    float2 o;
    o.x = a0 * r + b[32 * HALF + 2 * c];
    o.y = a1 * r + b[32 * HALF + 2 * c + 1];
    ((float2*)(out + (size_t)d * OUTF + 32 * HALF))[c] = o;
  }
}

// ---------------------------------------------------------------- launch
extern "C" void kernel_launch(void* const* d_in, const int* in_sizes, int n_in,
                              void* d_out, int out_size, void* d_ws, size_t ws_size,
                              hipStream_t stream) {
  const float* x   = (const float*)d_in[0];
  const int*   ei  = (const int*)d_in[1];
  const float* W1  = (const float*)d_in[2];
  const float* a1s = (const float*)d_in[3];
  const float* a1d = (const float*)d_in[4];
  const float* b1  = (const float*)d_in[5];
  const float* W2  = (const float*)d_in[6];
  const float* a2s = (const float*)d_in[7];
  const float* a2d = (const float*)d_in[8];
  const float* b2  = (const float*)d_in[9];
  float* out = (float*)d_out;

  const int N = in_sizes[0] / IN_F;
  const int E = in_sizes[1] / 2;
  const int ET = E + N;
  const int* srcI = ei;
  const int* dstI = ei + E;
  const int NB = (N + 127) >> 7;
  const int NG1 = (N + 63) / 64;

  // workspace layout
  int* rowptr  = (int*)d_ws;                  // N
  int* counts  = rowptr + N;                  // N
  int* csr     = counts + N;                  // ET
  unsigned* stage = (unsigned*)(csr + ET);    // E
  int* gbcnt   = (int*)(stage + E);           // NBMAX
  int* sbase   = gbcnt + NBMAX;               // NBMAX
  int* csrbase = sbase + NBMAX;               // NBMAX
  int* gcursor = csrbase + NBMAX;             // NBMAX
  size_t int_end = (size_t)(2 * N + ET + E + 4 * NBMAX);
  int_end = (int_end + 3) & ~(size_t)3;
  float* h1f   = (float*)d_ws + int_end;      // region: N*128 floats
  unsigned* h16 = (unsigned*)h1f;             // layer1: N*64 uints; layer2: N*32 uints
  unsigned short* xb = (unsigned short*)(h1f + (size_t)N * 64);      // N*128 bf16
  unsigned short* out1b = (unsigned short*)(h1f + (size_t)N * HID);  // N*128 bf16 (post-ELU)
  float* alf   = h1f + (size_t)N * HID + (size_t)N * 64;
  float* al1s_ = alf;                          // N*4
  float* al1d_ = al1s_ + (size_t)N * NH1;      // N*4
  float* al2s_ = al1d_ + (size_t)N * NH1;      // N
  float* al2d_ = al2s_ + N;                    // N
  unsigned short* wt  = (unsigned short*)(al2d_ + N);  // 128*128 bf16 swizzled
  unsigned short* wt2 = wt + IN_F * HID;               // 64*128 bf16 swizzled

  const int nx4 = N * IN_F / 4;
  const int nprep = (nx4 + 255) / 256;

  hipMemsetAsync(gbcnt, 0, NBMAX * sizeof(int), stream);
  k_pb<<<512 + nprep, 256, 0, stream>>>(x, W1, W2, dstI, E, xb, wt, wt2, gbcnt, nx4);
  k_bscan<<<1, 512, 0, stream>>>(gbcnt, sbase, gcursor, csrbase, NB, N);
  k_g1bf<<<NG1 + NBFILL, 256, 0, stream>>>(xb, wt, a1s, a1d, h16, al1s_, al1d_, N,
                                           srcI, dstI, E, gcursor, stage, NG1);
  k_build<<<NB, 256, 0, stream>>>(stage, sbase, gbcnt, csrbase, rowptr, counts, csr, N);

  const int ga = (N + 3) / 4;
  k_aggr1<0><<<ga, 256, 0, stream>>>(rowptr, counts, csr, al1s_, al1d_, h16, b1, out1b, N);
  k_aggr1<1><<<ga, 256, 0, stream>>>(rowptr, counts, csr, al1s_, al1d_, h16, b1, out1b, N);

  k_gemm2<<<(N + 63) / 64, 256, 0, stream>>>(out1b, wt2, a2s, a2d, h16, al2s_, al2d_, N);
  k_aggr2<0><<<ga, 256, 0, stream>>>(rowptr, counts, csr, al2s_, al2d_, h16, b2, out, N);
  k_aggr2<1><<<ga, 256, 0, stream>>>(rowptr, counts, csr, al2s_, al2d_, h16, b2, out, N);
}

// Round 15
// 137.359 us; speedup vs baseline: 1.3018x; 1.3018x over previous
//
#include <hip/hip_runtime.h>
#include <hip/hip_bf16.h>
#include <cstdint>
#include <cstddef>

#define IN_F 128
#define HID 128
#define NH1 4
#define OUTF 64
#define NBMAX 512   // buckets of 128 nodes -> supports N <= 65536
#define NHB 128     // histogram partial blocks
#define CH 2048     // edges per bfill chunk
#define NBFILL 256  // bfill blocks

typedef __attribute__((ext_vector_type(8))) short short8;
typedef __attribute__((ext_vector_type(4))) float f32x4;

__device__ __forceinline__ float lrelu(float v) { return v > 0.f ? v : 0.2f * v; }
__device__ __forceinline__ float eluf(float v) { return v > 0.f ? v : (__expf(v) - 1.f); }
__device__ __forceinline__ unsigned f2bf(float f) {
  unsigned u = __float_as_uint(f);
  return (u + 0x7fffu + ((u >> 16) & 1u)) >> 16;
}
__device__ __forceinline__ float bflo(unsigned hv) { return __uint_as_float(hv << 16); }
__device__ __forceinline__ float bfhi(unsigned hv) { return __uint_as_float(hv & 0xffff0000u); }

// ---------------------------------------------------------------- fused prep + bucket histogram
// blocks [0,NHB): per-block dst-bucket partial histogram (plain writes, no zeroing needed);
// blocks [NHB,..): x->bf16, W1/W2 -> bf16 T+swizzle
__global__ __launch_bounds__(256) void k_pb(
    const float* __restrict__ x, const float* __restrict__ W1, const float* __restrict__ W2,
    const int* __restrict__ dst, int E,
    unsigned short* __restrict__ xb, unsigned short* __restrict__ wt,
    unsigned short* __restrict__ wt2, int* __restrict__ part, int nx4) {
  __shared__ int bcnt[NBMAX];
  if (blockIdx.x < NHB) {
    const int t = threadIdx.x;
    bcnt[t] = 0; bcnt[t + 256] = 0;
    __syncthreads();
    for (int e = blockIdx.x * 256 + t; e < E; e += NHB * 256)
      atomicAdd(&bcnt[dst[e] >> 7], 1);
    __syncthreads();
    part[blockIdx.x * NBMAX + t] = bcnt[t];
    part[blockIdx.x * NBMAX + t + 256] = bcnt[t + 256];
    return;
  }
  const int t = (blockIdx.x - NHB) * 256 + threadIdx.x;
  if (t < nx4) {
    const float4 v = ((const float4*)x)[t];
    uint2 u;
    u.x = f2bf(v.x) | (f2bf(v.y) << 16);
    u.y = f2bf(v.z) | (f2bf(v.w) << 16);
    ((uint2*)xb)[t] = u;
  }
  if (t < IN_F * HID) {
    const int k = t >> 7, c = t & 127;
    const int chunk = k >> 3;
    const int csw = (chunk & 8) | ((chunk ^ (c & 7)) & 7);
    wt[c * 128 + csw * 8 + (k & 7)] = (unsigned short)f2bf(W1[t]);
  }
  if (t < HID * OUTF) {
    const int k = t >> 6, c = t & 63;
    const int chunk = k >> 3;
    const int csw = (chunk & 8) | ((chunk ^ (c & 7)) & 7);
    wt2[c * 128 + csw * 8 + (k & 7)] = (unsigned short)f2bf(W2[t]);
  }
}

// ---------------------------------------------------------------- bucket scan (one block, 512 thr)
// sums NHB partials per bucket, one exclusive scan; writes gbcnt/sbase/gcursor.
// (csr base is analytic: csrbase[b] = sbase[b] + 128*b.)
__global__ __launch_bounds__(512) void k_bscan(const int* __restrict__ part,
                                               int* __restrict__ gbcnt,
                                               int* __restrict__ sbase,
                                               int* __restrict__ gcursor, int NB) {
  __shared__ int tmp[NBMAX];
  const int t = threadIdx.x;
  int g = 0;
  for (int b = 0; b < NHB; ++b) g += part[b * NBMAX + t];
  tmp[t] = g;
  __syncthreads();
  #pragma unroll
  for (int off = 1; off < NBMAX; off <<= 1) {
    const int v = (t >= off) ? tmp[t - off] : 0;
    __syncthreads();
    tmp[t] += v;
    __syncthreads();
  }
  if (t < NB) {
    const int sb = tmp[t] - g;
    gbcnt[t] = g;
    sbase[t] = sb;
    gcursor[t] = sb;
  }
}

// ---------------------------------------------------------------- fused layer-1 MFMA GEMM + bfill
// h16 packed as col pairs (j, j+64): uint j holds cols (16nt+li, 16nt+li+64).
__global__ __launch_bounds__(256) void k_g1bf(
    const unsigned short* __restrict__ xb, const unsigned short* __restrict__ wt,
    const float* __restrict__ a_s, const float* __restrict__ a_d,
    unsigned* __restrict__ h16, float* __restrict__ als, float* __restrict__ ald, int N,
    const int* __restrict__ src, const int* __restrict__ dst, int E,
    int* __restrict__ gcursor, unsigned* __restrict__ stage, int NG1) {
  __shared__ __align__(16) unsigned char smem[32768];
  if ((int)blockIdx.x >= NG1) {
    int* bcnt = (int*)smem;
    int* bofs = bcnt + NBMAX;
    int* lcur = bofs + NBMAX;
    int* gofs = lcur + NBMAX;
    unsigned* obuf = (unsigned*)(smem + 8192);
    unsigned short* bid = (unsigned short*)(smem + 16384);
    const int t = threadIdx.x;
    const int b = blockIdx.x - NG1;
    for (int base_e = b * CH; base_e < E; base_e += NBFILL * CH) {
      const int cnt = min(CH, E - base_e);
      __syncthreads();
      bcnt[t] = 0; bcnt[t + 256] = 0;
      __syncthreads();
      for (int i = t; i < cnt; i += 256)
        atomicAdd(&bcnt[dst[base_e + i] >> 7], 1);
      __syncthreads();
      bofs[t] = bcnt[t]; bofs[t + 256] = bcnt[t + 256];
      __syncthreads();
      #pragma unroll
      for (int off = 1; off < NBMAX; off <<= 1) {
        const int v0 = (t >= off) ? bofs[t - off] : 0;
        const int v1 = (t + 256 >= off) ? bofs[t + 256 - off] : 0;
        __syncthreads();
        bofs[t] += v0; bofs[t + 256] += v1;
        __syncthreads();
      }
      {
        const int e0 = bofs[t] - bcnt[t], e1 = bofs[t + 256] - bcnt[t + 256];
        __syncthreads();
        bofs[t] = e0;        bofs[t + 256] = e1;
        lcur[t] = e0;        lcur[t + 256] = e1;
      }
      __syncthreads();
      for (int i = t; i < cnt; i += 256) {
        const int d = dst[base_e + i];
        const int bb = d >> 7;
        const int pos = atomicAdd(&lcur[bb], 1);
        obuf[pos] = ((unsigned)(d & 127) << 25) | (unsigned)src[base_e + i];
        bid[pos] = (unsigned short)bb;
      }
      __syncthreads();
      for (int bb = t; bb < NBMAX; bb += 256)
        if (bcnt[bb] > 0) gofs[bb] = atomicAdd(&gcursor[bb], bcnt[bb]);
      __syncthreads();
      for (int i = t; i < cnt; i += 256) {
        const int bb = bid[i];
        stage[gofs[bb] + (i - bofs[bb])] = obuf[i];
      }
    }
    return;
  }
  // ---- gemm1 body ----
  unsigned short* Wl = (unsigned short*)smem;
  const int wave = threadIdx.x >> 6, lane = threadIdx.x & 63;
  for (int i = threadIdx.x * 8; i < IN_F * HID; i += 256 * 8)
    *(short8*)(Wl + i) = *(const short8*)(wt + i);
  __syncthreads();
  const int li = lane & 15, g = lane >> 4;
  const int r0w = blockIdx.x * 64 + wave * 16;
  if (r0w >= N) return;
  float asp[8], adp[8];
  #pragma unroll
  for (int nt = 0; nt < 8; ++nt) { asp[nt] = a_s[16 * nt + li]; adp[nt] = a_d[16 * nt + li]; }
  f32x4 acc[8];
  #pragma unroll
  for (int nt = 0; nt < 8; ++nt) acc[nt] = (f32x4){0.f, 0.f, 0.f, 0.f};
  const int arow = min(r0w + li, N - 1);
  const unsigned short* xrow = xb + (size_t)arow * IN_F;
  #pragma unroll
  for (int s = 0; s < 4; ++s) {
    const short8 a = *(const short8*)(xrow + 32 * s + g * 8);
    const int chunk = 4 * s + g;
    const int csw = (chunk & 8) | ((chunk ^ (li & 7)) & 7);
    const unsigned short* bbase = Wl + li * 128 + csw * 8;
    #pragma unroll
    for (int nt = 0; nt < 8; ++nt) {
      const short8 bfr = *(const short8*)(bbase + nt * 2048);
      acc[nt] = __builtin_amdgcn_mfma_f32_16x16x32_bf16(a, bfr, acc[nt], 0, 0, 0);
    }
  }
  #pragma unroll
  for (int r = 0; r < 4; ++r) {
    const int row = r0w + g * 4 + r;
    if (row < N) {
      #pragma unroll
      for (int nt = 0; nt < 4; ++nt) {
        const unsigned u = f2bf(acc[nt][r]) | (f2bf(acc[nt + 4][r]) << 16);
        h16[(size_t)row * 64 + 16 * nt + li] = u;
      }
    }
  }
  #pragma unroll
  for (int r = 0; r < 4; ++r) {
    const int row = r0w + g * 4 + r;
    #pragma unroll
    for (int hh = 0; hh < 4; ++hh) {
      float ps = acc[2 * hh][r] * asp[2 * hh] + acc[2 * hh + 1][r] * asp[2 * hh + 1];
      float pd = acc[2 * hh][r] * adp[2 * hh] + acc[2 * hh + 1][r] * adp[2 * hh + 1];
      #pragma unroll
      for (int mk = 1; mk <= 8; mk <<= 1) {
        ps += __shfl_xor(ps, mk, 16);
        pd += __shfl_xor(pd, mk, 16);
      }
      if (li == 0 && row < N) {
        als[row * NH1 + hh] = ps;
        ald[row * NH1 + hh] = pd;
      }
    }
  }
}

// ---------------------------------------------------------------- per-bucket CSR finalize
__global__ __launch_bounds__(256) void k_build(const unsigned* __restrict__ stage,
                                               const int* __restrict__ sbase,
                                               const int* __restrict__ gbcnt,
                                               int* __restrict__ rowptr,
                                               int* __restrict__ counts,
                                               int* __restrict__ csr, int N) {
  __shared__ int lc[128], lofs[128], lcur[128];
  const int b = blockIdx.x;
  const int t = threadIdx.x;
  const int n0 = b << 7;
  const int nn = min(128, N - n0);
  if (t < 128) lc[t] = (t < nn) ? 1 : 0;
  __syncthreads();
  const int s0 = sbase[b], ecnt = gbcnt[b];
  for (int i = t; i < ecnt; i += 256)
    atomicAdd(&lc[stage[s0 + i] >> 25], 1);
  __syncthreads();
  if (t < 128) lofs[t] = lc[t];
  __syncthreads();
  #pragma unroll
  for (int off = 1; off < 128; off <<= 1) {
    const int v = (t >= off && t < 128) ? lofs[t - off] : 0;
    __syncthreads();
    if (t < 128) lofs[t] += v;
    __syncthreads();
  }
  const int base = s0 + (b << 7);  // csrbase[b] = sbase[b] + 128*b
  if (t < nn) {
    const int ex = lofs[t] - lc[t];
    const int r = base + ex;
    rowptr[n0 + t] = r;
    counts[n0 + t] = lc[t];
    csr[r] = n0 + t;
    lcur[t] = ex + 1;
  }
  __syncthreads();
  for (int i = t; i < ecnt; i += 256) {
    const unsigned e = stage[s0 + i];
    const int d = e >> 25;
    const int pos = atomicAdd(&lcur[d], 1);
    csr[base + pos] = (int)(e & 0x1FFFFFFu);
  }
}

// ---------------------------------------------------------------- layer-2 GEMM: bf16 MFMA
__global__ __launch_bounds__(256) void k_gemm2(
    const unsigned short* __restrict__ hb, const unsigned short* __restrict__ wt2,
    const float* __restrict__ a_s, const float* __restrict__ a_d,
    unsigned* __restrict__ h16, float* __restrict__ als, float* __restrict__ ald, int N) {
  __shared__ unsigned short Wl[OUTF * HID];  // 16 KB
  const int wave = threadIdx.x >> 6, lane = threadIdx.x & 63;
  for (int i = threadIdx.x * 8; i < OUTF * HID; i += 256 * 8)
    *(short8*)(Wl + i) = *(const short8*)(wt2 + i);
  __syncthreads();
  const int li = lane & 15, g = lane >> 4;
  const int r0w = blockIdx.x * 64 + wave * 16;
  if (r0w >= N) return;
  float asp[4], adp[4];
  #pragma unroll
  for (int nt = 0; nt < 4; ++nt) { asp[nt] = a_s[16 * nt + li]; adp[nt] = a_d[16 * nt + li]; }
  f32x4 acc[4];
  #pragma unroll
  for (int nt = 0; nt < 4; ++nt) acc[nt] = (f32x4){0.f, 0.f, 0.f, 0.f};
  const int arow = min(r0w + li, N - 1);
  const unsigned short* xrow = hb + (size_t)arow * HID;
  #pragma unroll
  for (int s = 0; s < 4; ++s) {
    const short8 a = *(const short8*)(xrow + 32 * s + g * 8);
    const int chunk = 4 * s + g;
    const int csw = (chunk & 8) | ((chunk ^ (li & 7)) & 7);
    const unsigned short* bbase = Wl + li * 128 + csw * 8;
    #pragma unroll
    for (int nt = 0; nt < 4; ++nt) {
      const short8 bfr = *(const short8*)(bbase + nt * 2048);
      acc[nt] = __builtin_amdgcn_mfma_f32_16x16x32_bf16(a, bfr, acc[nt], 0, 0, 0);
    }
  }
  // h2: adjacent col pairs (2c,2c+1) via lane-pair exchange
  #pragma unroll
  for (int r = 0; r < 4; ++r) {
    const int row = r0w + g * 4 + r;
    #pragma unroll
    for (int nt = 0; nt < 4; ++nt) {
      const float v = acc[nt][r];
      const float vn = __shfl_xor(v, 1, 64);
      if (!(li & 1) && row < N)
        h16[(size_t)row * 32 + 8 * nt + (li >> 1)] = f2bf(v) | (f2bf(vn) << 16);
    }
  }
  #pragma unroll
  for (int r = 0; r < 4; ++r) {
    const int row = r0w + g * 4 + r;
    float ps = 0.f, pd = 0.f;
    #pragma unroll
    for (int nt = 0; nt < 4; ++nt) { ps += acc[nt][r] * asp[nt]; pd += acc[nt][r] * adp[nt]; }
    #pragma unroll
    for (int mk = 1; mk <= 8; mk <<= 1) {
      ps += __shfl_xor(ps, mk, 16);
      pd += __shfl_xor(pd, mk, 16);
    }
    if (li == 0 && row < N) { als[row] = ps; ald[row] = pd; }
  }
}

// ---------------------------------------------------------------- fused softmax+gather, layer 1
// wave-autonomous, zero LDS/barriers; h16 pairing (col lane, col lane+64);
// writes out1 as packed bf16.
__global__ __launch_bounds__(256) void k_aggr1(
    const int* __restrict__ rowptr, const int* __restrict__ counts,
    const int* __restrict__ csr,
    const float* __restrict__ als, const float* __restrict__ ald,
    const unsigned* __restrict__ h16, const float* __restrict__ b,
    unsigned short* __restrict__ outb, int N) {
  const int lane = threadIdx.x & 63;
  const int d = blockIdx.x * 4 + (threadIdx.x >> 6);
  if (d >= N) return;
  const int row0 = rowptr[d], deg = counts[d];
  const int headE = lane & 3;
  const float aldE = ald[d * NH1 + headE];
  const int hx = lane >> 5, hy = 2 + hx;
  const float bx = b[lane], by = b[lane + 64];
  float psum = 0.f, ax = 0.f, ay = 0.f;
  int i = 0;
  for (; i + 8 <= deg; i += 8) {
    const int sl = (lane < 8) ? csr[row0 + i + lane] : 0;
    const int se = __shfl(sl, lane >> 2, 64);
    const float pv = __expf(lrelu(als[se * NH1 + headE] + aldE));
    if (lane < 32) psum += pv;
    #pragma unroll
    for (int j = 0; j < 8; ++j) {
      const int s = __builtin_amdgcn_readfirstlane(__shfl(sl, j, 64));
      const unsigned hv = h16[(size_t)s * 64 + lane];
      const float px = __shfl(pv, 4 * j + hx, 64);
      const float py = __shfl(pv, 4 * j + hy, 64);
      ax += px * bflo(hv);
      ay += py * bfhi(hv);
    }
  }
  if (i < deg) {
    const int rem = deg - i;
    const int sl = (lane < 8) ? csr[row0 + i + min(lane, rem - 1)] : 0;
    const int se = __shfl(sl, lane >> 2, 64);
    float pv = __expf(lrelu(als[se * NH1 + headE] + aldE));
    if ((lane >> 2) >= rem) pv = 0.f;
    if (lane < 32) psum += pv;
    #pragma unroll
    for (int j = 0; j < 8; ++j) {
      const int s = __builtin_amdgcn_readfirstlane(__shfl(sl, j, 64));
      const unsigned hv = h16[(size_t)s * 64 + lane];
      const float px = __shfl(pv, 4 * j + hx, 64);
      const float py = __shfl(pv, 4 * j + hy, 64);
      ax += px * bflo(hv);
      ay += py * bfhi(hv);
    }
  }
  #pragma unroll
  for (int mk = 4; mk <= 16; mk <<= 1) psum += __shfl_xor(psum, mk, 32);
  const float sumx = __shfl(psum, hx, 64);
  const float sumy = __shfl(psum, hy, 64);
  outb[(size_t)d * HID + lane]      = (unsigned short)f2bf(eluf(ax / (sumx + 1e-16f) + bx));
  outb[(size_t)d * HID + 64 + lane] = (unsigned short)f2bf(eluf(ay / (sumy + 1e-16f) + by));
}

// ---------------------------------------------------------------- fused softmax+gather, layer 2 (H=1)
__global__ __launch_bounds__(256) void k_aggr2(
    const int* __restrict__ rowptr, const int* __restrict__ counts,
    const int* __restrict__ csr,
    const float* __restrict__ als, const float* __restrict__ ald,
    const unsigned* __restrict__ h16, const float* __restrict__ b,
    float* __restrict__ out, int N) {
  const int lane = threadIdx.x & 63;
  const int d = blockIdx.x * 4 + (threadIdx.x >> 6);
  if (d >= N) return;
  const int row0 = rowptr[d], deg = counts[d];
  const float aldd = ald[d];
  const int eo = lane >> 5;
  const int c = lane & 31;
  float psum = 0.f, a0 = 0.f, a1 = 0.f;
  int i = 0;
  for (; i + 16 <= deg; i += 16) {
    const int sl = (lane < 16) ? csr[row0 + i + lane] : 0;
    const float pv = __expf(lrelu(als[sl] + aldd));
    if (lane < 16) psum += pv;
    #pragma unroll
    for (int q = 0; q < 8; ++q) {
      const int s = __shfl(sl, 2 * q + eo, 64);
      const float p = __shfl(pv, 2 * q + eo, 64);
      const unsigned hv = h16[(size_t)s * (OUTF / 2) + c];
      a0 += p * bflo(hv);
      a1 += p * bfhi(hv);
    }
  }
  if (i < deg) {
    const int rem = deg - i;
    const int sl = (lane < 16) ? csr[row0 + i + min(lane, rem - 1)] : 0;
    float pv = __expf(lrelu(als[sl] + aldd));
    if (lane >= rem) pv = 0.f;
    if (lane < 16) psum += pv;
    #pragma unroll
    for (int q = 0; q < 8; ++q) {
      const int s = __shfl(sl, 2 * q + eo, 64);
      const float p = __shfl(pv, 2 * q + eo, 64);
      const unsigned hv = h16[(size_t)s * (OUTF / 2) + c];
      a0 += p * bflo(hv);
      a1 += p * bfhi(hv);
    }
  }
  #pragma unroll
  for (int mk = 1; mk <= 8; mk <<= 1) psum += __shfl_xor(psum, mk, 16);
  a0 += __shfl_xor(a0, 32, 64);
  a1 += __shfl_xor(a1, 32, 64);
  if (lane < 32) {
    const float r = 1.f / (__shfl(psum, 0, 64) + 1e-16f);
    float2 o;
    o.x = a0 * r + b[2 * c];
    o.y = a1 * r + b[2 * c + 1];
    *(float2*)(out + (size_t)d * OUTF + 2 * c) = o;
  }
}

// ---------------------------------------------------------------- launch
extern "C" void kernel_launch(void* const* d_in, const int* in_sizes, int n_in,
                              void* d_out, int out_size, void* d_ws, size_t ws_size,
                              hipStream_t stream) {
  const float* x   = (const float*)d_in[0];
  const int*   ei  = (const int*)d_in[1];
  const float* W1  = (const float*)d_in[2];
  const float* a1s = (const float*)d_in[3];
  const float* a1d = (const float*)d_in[4];
  const float* b1  = (const float*)d_in[5];
  const float* W2  = (const float*)d_in[6];
  const float* a2s = (const float*)d_in[7];
  const float* a2d = (const float*)d_in[8];
  const float* b2  = (const float*)d_in[9];
  float* out = (float*)d_out;

  const int N = in_sizes[0] / IN_F;
  const int E = in_sizes[1] / 2;
  const int ET = E + N;
  const int* srcI = ei;
  const int* dstI = ei + E;
  const int NB = (N + 127) >> 7;
  const int NG1 = (N + 63) / 64;

  // workspace layout
  int* rowptr  = (int*)d_ws;                  // N
  int* counts  = rowptr + N;                  // N
  int* csr     = counts + N;                  // ET
  unsigned* stage = (unsigned*)(csr + ET);    // E
  int* part    = (int*)(stage + E);           // NHB*NBMAX
  int* gbcnt   = part + NHB * NBMAX;          // NBMAX
  int* sbase   = gbcnt + NBMAX;               // NBMAX
  int* gcursor = sbase + NBMAX;               // NBMAX
  size_t int_end = (size_t)(2 * N + ET + E + NHB * NBMAX + 3 * NBMAX);
  int_end = (int_end + 3) & ~(size_t)3;
  float* h1f   = (float*)d_ws + int_end;      // region: N*128 floats
  unsigned* h16 = (unsigned*)h1f;             // layer1: N*64 uints; layer2: N*32 uints
  unsigned short* xb = (unsigned short*)(h1f + (size_t)N * 64);      // N*128 bf16
  unsigned short* out1b = (unsigned short*)(h1f + (size_t)N * HID);  // N*128 bf16 (post-ELU)
  float* alf   = h1f + (size_t)N * HID + (size_t)N * 64;
  float* al1s_ = alf;                          // N*4
  float* al1d_ = al1s_ + (size_t)N * NH1;      // N*4
  float* al2s_ = al1d_ + (size_t)N * NH1;      // N
  float* al2d_ = al2s_ + N;                    // N
  unsigned short* wt  = (unsigned short*)(al2d_ + N);  // 128*128 bf16 swizzled
  unsigned short* wt2 = wt + IN_F * HID;               // 64*128 bf16 swizzled

  const int nx4 = N * IN_F / 4;
  const int nprep = (nx4 + 255) / 256;

  // fused prep + partial histogram (no memset needed; partials are plain writes)
  k_pb<<<NHB + nprep, 256, 0, stream>>>(x, W1, W2, dstI, E, xb, wt, wt2, part, nx4);
  k_bscan<<<1, 512, 0, stream>>>(part, gbcnt, sbase, gcursor, NB);
  // fused layer-1 MFMA GEMM + binning pass
  k_g1bf<<<NG1 + NBFILL, 256, 0, stream>>>(xb, wt, a1s, a1d, h16, al1s_, al1d_, N,
                                           srcI, dstI, E, gcursor, stage, NG1);
  k_build<<<NB, 256, 0, stream>>>(stage, sbase, gbcnt, rowptr, counts, csr, N);

  k_aggr1<<<(N + 3) / 4, 256, 0, stream>>>(rowptr, counts, csr, al1s_, al1d_, h16, b1, out1b, N);

  k_gemm2<<<(N + 63) / 64, 256, 0, stream>>>(out1b, wt2, a2s, a2d, h16, al2s_, al2d_, N);
  k_aggr2<<<(N + 3) / 4, 256, 0, stream>>>(rowptr, counts, csr, al2s_, al2d_, h16, b2, out, N);
}